// Round 8
// baseline (168.897 us; speedup 1.0000x reference)
//
#include <hip/hip_runtime.h>
#include <math.h>

#define NROWS 16384
#define DT_C 0.01f

typedef short s16x8 __attribute__((ext_vector_type(8)));
typedef float f32x4 __attribute__((ext_vector_type(4)));
typedef float f32x2 __attribute__((ext_vector_type(2)));

__device__ __forceinline__ unsigned short f2bf(float f) {
    unsigned u = __float_as_uint(f);
    u += 0x7fffu + ((u >> 16) & 1u);
    return (unsigned short)(u >> 16);
}
__device__ __forceinline__ unsigned pack2bf(float a, float b) {
    return (unsigned)f2bf(a) | ((unsigned)f2bf(b) << 16);
}
// VALU-pipe cross-lane adds via DPP (no LDS pipe).
// sum8: xor1 (0xB1), xor2 (0x4E), row_half_mirror (0x141).
// sum16: + row_mirror (0x140).
template <int CTRL>
__device__ __forceinline__ float dppadd(float v) {
    int x = __builtin_amdgcn_update_dpp(0, __float_as_int(v), CTRL, 0xF, 0xF, true);
    return v + __int_as_float(x);
}
__device__ __forceinline__ float sum8(float p) {
    p = dppadd<0xB1>(p);
    p = dppadd<0x4E>(p);
    p = dppadd<0x141>(p);
    return p;
}
__device__ __forceinline__ float sum16(float p) {
    p = dppadd<0xB1>(p);
    p = dppadd<0x4E>(p);
    p = dppadd<0x141>(p);
    p = dppadd<0x140>(p);
    return p;
}
// Raw wave-counting barrier with explicit drain (verified plain-HIP idiom:
// learn_hip m201 8-phase template). No compiler convergence contract —
// safe in divergent-but-count-matched control flow.
__device__ __forceinline__ void bsync() {
    asm volatile("s_waitcnt lgkmcnt(0) vmcnt(0)" ::: "memory");
    __builtin_amdgcn_s_barrier();
}

// ---------------------------------------------------------------------------
// Prep: pack stage-B weights to bf16 flat [stage][k8][n][8] (k = k8*8+j).
// s=0: W_feat1[0:256], s=1: W_feat2, s=2: [W_xim1 | W_xil1].
// ---------------------------------------------------------------------------
__global__ __launch_bounds__(256) void prep_k(
    const float* __restrict__ Wf1, const float* __restrict__ Wf2,
    const float* __restrict__ Wm1, const float* __restrict__ Wl1,
    const float* __restrict__ bm1, const float* __restrict__ bl1,
    unsigned short* __restrict__ wpack, float* __restrict__ biasH)
{
    const int id = blockIdx.x * 256 + threadIdx.x;   // 0..24575
    const int n  = id & 255;
    const int k8 = (id >> 8) & 31;
    const int s  = id >> 13;

    unsigned short tmp[8];
    #pragma unroll
    for (int j = 0; j < 8; ++j) {
        const int k = k8 * 8 + j;
        float v;
        if (s == 0)      v = Wf1[k * 256 + n];
        else if (s == 1) v = Wf2[k * 256 + n];
        else             v = (n < 128) ? Wm1[k * 128 + n] : Wl1[k * 128 + n - 128];
        tmp[j] = f2bf(v);
    }
    *(uint4*)&wpack[((s * 32 + k8) * 256 + n) * 8] = *(const uint4*)tmp;

    if (id < 256) biasH[id] = (id < 128) ? bm1[id] : bl1[id - 128];
}

// ---------------------------------------------------------------------------
// Fused kernel, 768 threads (12 waves) per 32-row block:
//   waves 4-11 (512 thr): ODE scan, 16 lanes/row (4 MLP units/lane,
//     sum16 DPP reduce), raw y -> LDS yraw[32][256]. 4096 scan waves total
//     = 4/SIMD: scan hides scan.
//   waves 0-3 (256 thr): stage data->LDS frags; MFMA h1->feat->heads;
//     128-dots -> xi.
//   Sync: raw s_barrier (bsync) paired BY COUNT across the divergent halves
//   (scan side: 6 barriers through its 8 chunks + final join; MFMA side:
//   B0,B1,B2,B3a,B3,B4 + final join = 7 each).
//   Joint epilogue decays yraw from LDS, writes xout exactly once.
// ---------------------------------------------------------------------------
__global__ __launch_bounds__(768, 6) void fused_k(
    const float* __restrict__ data, const float* __restrict__ omega,
    const float* __restrict__ eps_g,
    const unsigned short* __restrict__ wpack, const float* __restrict__ biasH,
    const float* __restrict__ bf1, const float* __restrict__ bf2,
    const float* __restrict__ w256g,
    const float* __restrict__ Wm2, const float* __restrict__ bm2,
    const float* __restrict__ Wl2, const float* __restrict__ bl2,
    const float* __restrict__ Wa1, const float* __restrict__ ba1,
    const float* __restrict__ Wa2, const float* __restrict__ ba2,
    float* __restrict__ out_mean, float* __restrict__ out_lnvar,
    float* __restrict__ xout)
{
    // 64.25KB LDS: headsF aliases As1+Hs (dead by heads phase); yraw separate.
    // 2 blocks/CU -> 128.5KB/CU (<160).
    __shared__ __align__(16) unsigned char smem[65792];
    unsigned short* As1 = (unsigned short*)smem;            // 16KB frags: data, then feat
    unsigned short* Hs  = (unsigned short*)(smem + 16384);  // 16KB frags: h1
    float* headsF = (float*)smem;                           // 32KB alias: heads f32
    float* omg = (float*)(smem + 32768);
    float* xiS = omg + 32;
    float* yraw = (float*)(smem + 33024);                   // [32][256] raw y

    const int tid  = threadIdx.x;
    const int wid  = tid >> 6;
    const int lane = tid & 63;
    const int ln   = lane & 15;
    const int quad = lane >> 4;
    const int r0   = blockIdx.x * 32;

    if (wid >= 4) {
        // ===================================================================
        // SCAN WAVES (4..11): 16 lanes/row, raw y -> LDS.
        // ===================================================================
        const int st  = tid - 256;       // 0..511
        const int r   = st >> 4;         // row 0..31
        const int l   = st & 15;         // 16 lanes/row, units i = l*4..l*4+3
        const int row = r0 + r;
        const float om = omega[row];
        const float pseed = ba2[0] * 0.0625f;   // /16

        const int i0 = l * 4;
        const f32x2 w0a = *(const f32x2*)&Wa1[i0];
        const f32x2 w0b = *(const f32x2*)&Wa1[i0 + 2];
        const f32x2 bba = *(const f32x2*)&ba1[i0];
        const f32x2 bbb = *(const f32x2*)&ba1[i0 + 2];
        const f32x2 w1a = *(const f32x2*)&Wa1[64 + i0];
        const f32x2 w1b = *(const f32x2*)&Wa1[64 + i0 + 2];
        const f32x2 w2a = *(const f32x2*)&Wa2[i0];
        const f32x2 w2b = *(const f32x2*)&Wa2[i0 + 2];
        const f32x2 Aa  = f32x2{fmaf(om, w0a.x, bba.x), fmaf(om, w0a.y, bba.y)};
        const f32x2 Ab  = f32x2{fmaf(om, w0b.x, bbb.x), fmaf(om, w0b.y, bbb.y)};

        auto partial = [&](float y) -> float {
            const f32x2 y2 = f32x2{y, y};
            f32x2 acc2 = f32x2{pseed, 0.f};
            f32x2 h = __builtin_elementwise_fma(y2, w1a, Aa);
            h = __builtin_elementwise_max(h, f32x2{0.f, 0.f});
            acc2 = __builtin_elementwise_fma(h, w2a, acc2);
            f32x2 g = __builtin_elementwise_fma(y2, w1b, Ab);
            g = __builtin_elementwise_max(g, f32x2{0.f, 0.f});
            acc2 = __builtin_elementwise_fma(g, w2b, acc2);
            return acc2.x + acc2.y;
        };

        const float y0 = data[(size_t)row * 256];
        float ym = y0;          // y_t
        float yc = y0;          // y_{t+1}  (v0 = 0)
        const float DT2 = DT_C * DT_C;
        float pr = sum16(partial(ym));

        float* yrow = yraw + r * 256;
        for (int tb = 0; tb < 8; ++tb) {
            float cur[2];
            #pragma unroll
            for (int j = 0; j < 32; ++j) {
                if ((j >> 1) == l) cur[j & 1] = ym;    // compile-time index
                float pn = sum16(partial(yc));
                const float ynext = fmaf(DT2, pr, fmaf(2.f, yc, -ym));
                ym = yc; yc = ynext; pr = pn;          // pr consumed next step
            }
            *(f32x2*)&yrow[tb * 32 + l * 2] = f32x2{cur[0], cur[1]};
            if (tb < 6) bsync();                       // pair with MFMA B0..B4
        }
    } else {
        // ===================================================================
        // MFMA WAVES (0..3), tid 0..255
        // ===================================================================

        // ---- stage data -> As1 (coalesced, swizzled frag pack)
        {
            #pragma unroll
            for (int g2 = 0; g2 < 8; ++g2) {
                const int unit = g2 * 256 + tid;     // 16B unit over 32x256 f32
                const int m    = unit >> 6;
                const int c16  = unit & 63;
                const int kblk = c16 >> 1;
                const int h    = c16 & 1;
                const float4 v = *(const float4*)&data[(size_t)(r0 + m) * 256 + c16 * 4];
                unsigned* d = (unsigned*)&As1[((kblk * 32) + (m ^ (kblk & 7))) * 8 + h * 4];
                d[0] = pack2bf(v.x, v.y);
                d[1] = pack2bf(v.z, v.w);
            }
            if (tid < 32) omg[tid] = omega[r0 + tid];
        }
        bsync();                                       // B0: As1 + omg ready

        // ---- MFMA phases
        f32x4 acc[2][4];

        auto seed = [&](const float* bias) {
            #pragma unroll
            for (int nt = 0; nt < 4; ++nt) {
                const float b = bias[wid * 64 + nt * 16 + ln];
                acc[0][nt] = f32x4{b, b, b, b};
                acc[1][nt] = acc[0][nt];
            }
        };

        // A-frags from LDS, B-frags straight from global (L2-resident)
        auto run_stage = [&](const unsigned short* Ap, const unsigned short* wp) {
            #pragma unroll
            for (int c = 0; c < 4; ++c) {
                #pragma unroll
                for (int kk = 0; kk < 2; ++kk) {
                    const int kb   = kk * 4 + quad;
                    const int kblk = c * 8 + kb;
                    const int f    = kblk & 7;
                    s16x8 b0 = *(const s16x8*)&wp[((size_t)(kblk * 256) + wid * 64 + 0 * 16 + ln) * 8];
                    s16x8 b1 = *(const s16x8*)&wp[((size_t)(kblk * 256) + wid * 64 + 1 * 16 + ln) * 8];
                    s16x8 b2 = *(const s16x8*)&wp[((size_t)(kblk * 256) + wid * 64 + 2 * 16 + ln) * 8];
                    s16x8 b3 = *(const s16x8*)&wp[((size_t)(kblk * 256) + wid * 64 + 3 * 16 + ln) * 8];
                    s16x8 a0 = *(const s16x8*)&Ap[(kblk * 32 + (ln ^ f)) * 8];
                    s16x8 a1 = *(const s16x8*)&Ap[(kblk * 32 + ((ln ^ f) + 16)) * 8];
                    acc[0][0] = __builtin_amdgcn_mfma_f32_16x16x32_bf16(a0, b0, acc[0][0], 0, 0, 0);
                    acc[1][0] = __builtin_amdgcn_mfma_f32_16x16x32_bf16(a1, b0, acc[1][0], 0, 0, 0);
                    acc[0][1] = __builtin_amdgcn_mfma_f32_16x16x32_bf16(a0, b1, acc[0][1], 0, 0, 0);
                    acc[1][1] = __builtin_amdgcn_mfma_f32_16x16x32_bf16(a1, b1, acc[1][1], 0, 0, 0);
                    acc[0][2] = __builtin_amdgcn_mfma_f32_16x16x32_bf16(a0, b2, acc[0][2], 0, 0, 0);
                    acc[1][2] = __builtin_amdgcn_mfma_f32_16x16x32_bf16(a1, b2, acc[1][2], 0, 0, 0);
                    acc[0][3] = __builtin_amdgcn_mfma_f32_16x16x32_bf16(a0, b3, acc[0][3], 0, 0, 0);
                    acc[1][3] = __builtin_amdgcn_mfma_f32_16x16x32_bf16(a1, b3, acc[1][3], 0, 0, 0);
                }
            }
        };

        auto write_packed = [&](unsigned short* dst, bool addOm) {
            #pragma unroll
            for (int nt = 0; nt < 4; ++nt) {
                const int col = wid * 64 + nt * 16 + ln;
                const int kg  = col >> 3, f = kg & 7, jj = col & 7;
                const float wo = addOm ? w256g[col] : 0.f;
                #pragma unroll
                for (int mt = 0; mt < 2; ++mt) {
                    #pragma unroll
                    for (int r = 0; r < 4; ++r) {
                        const int row = mt * 16 + quad * 4 + r;
                        float v = acc[mt][nt][r];
                        if (addOm) v = fmaf(omg[row], wo, v);
                        v = fmaxf(v, 0.f);
                        dst[(kg * 32 + (row ^ f)) * 8 + jj] = f2bf(v);
                    }
                }
            }
        };

        seed(bf1);
        run_stage(As1, wpack);
        write_packed(Hs, true);
        bsync();                                       // B1: Hs ready
        seed(bf2);
        run_stage(Hs, wpack + 65536);
        write_packed(As1, false);
        bsync();                                       // B2: As1(feat) ready
        seed(biasH);
        run_stage(As1, wpack + 131072);
        bsync();                                       // B3a: done with As1/Hs (alias!)
        #pragma unroll
        for (int nt = 0; nt < 4; ++nt) {
            const int col = wid * 64 + nt * 16 + ln;
            #pragma unroll
            for (int mt = 0; mt < 2; ++mt) {
                #pragma unroll
                for (int r = 0; r < 4; ++r) {
                    const int row = mt * 16 + quad * 4 + r;
                    headsF[row * 256 + ((col + row * 8) & 255)] = fmaxf(acc[mt][nt][r], 0.f);
                }
            }
        }
        bsync();                                       // B3: heads ready

        // ---- 128-dot heads: 8 lanes/row -> xi
        {
            const int m = tid >> 3, l = tid & 7;
            float pm = 0.f, pl = 0.f;
            #pragma unroll
            for (int q = 0; q < 4; ++q) {
                const int c0 = l * 16 + q * 4;
                const float4 hm = *(const float4*)&headsF[m * 256 + ((c0 + m * 8) & 255)];
                const float4 wm = *(const float4*)&Wm2[c0];
                const float4 hl = *(const float4*)&headsF[m * 256 + ((128 + c0 + m * 8) & 255)];
                const float4 wl = *(const float4*)&Wl2[c0];
                pm = fmaf(hm.w, wm.w, fmaf(hm.z, wm.z, fmaf(hm.y, wm.y, fmaf(hm.x, wm.x, pm))));
                pl = fmaf(hl.w, wl.w, fmaf(hl.z, wl.z, fmaf(hl.y, wl.y, fmaf(hl.x, wl.x, pl))));
            }
            pm = sum8(pm);
            pl = sum8(pl);
            if (l == 0) {
                const float xm  = pm + bm2[0];
                const float mean = fmaxf(xm, 0.f) + log1pf(expf(-fabsf(xm)));
                const float lnv  = pl + bl2[0];
                out_mean[r0 + m]  = mean;
                out_lnvar[r0 + m] = lnv;
                float xi = mean + expf(0.5f * lnv) * eps_g[r0 + m];
                xiS[m] = fminf(fmaxf(xi, 0.f), 1.f);
            }
        }
        bsync();                                       // B4: xiS ready
    }

    bsync();                             // FINAL join: yraw + xiS ready

    // ---- joint epilogue (tid<512): decay yraw from LDS, single write.
    if (tid < 512) {
        const int r = tid >> 4;          // row 0..31
        const int l = tid & 15;          // 16 lanes/row
        const float nxdt = -xiS[r] * DT_C;
        const float* yr = yraw + r * 256;
        float* orow = xout + (size_t)(r0 + r) * 256;
        #pragma unroll
        for (int q = 0; q < 4; ++q) {
            const int c0 = q * 64 + l * 4;
            float4 v = *(const float4*)&yr[c0];
            v.x *= __expf(nxdt * (float)(c0 + 0));
            v.y *= __expf(nxdt * (float)(c0 + 1));
            v.z *= __expf(nxdt * (float)(c0 + 2));
            v.w *= __expf(nxdt * (float)(c0 + 3));
            *(float4*)&orow[c0] = v;
        }
    }
}

// ---------------------------------------------------------------------------
extern "C" void kernel_launch(void* const* d_in, const int* in_sizes, int n_in,
                              void* d_out, int out_size, void* d_ws, size_t ws_size,
                              hipStream_t stream)
{
    const float* data    = (const float*)d_in[0];
    const float* omega   = (const float*)d_in[1];
    const float* eps     = (const float*)d_in[2];
    const float* W_feat1 = (const float*)d_in[3];
    const float* b_feat1 = (const float*)d_in[4];
    const float* W_feat2 = (const float*)d_in[5];
    const float* b_feat2 = (const float*)d_in[6];
    const float* W_xim1  = (const float*)d_in[7];
    const float* b_xim1  = (const float*)d_in[8];
    const float* W_xim2  = (const float*)d_in[9];
    const float* b_xim2  = (const float*)d_in[10];
    const float* W_xil1  = (const float*)d_in[11];
    const float* b_xil1  = (const float*)d_in[12];
    const float* W_xil2  = (const float*)d_in[13];
    const float* b_xil2  = (const float*)d_in[14];
    const float* W_aux1  = (const float*)d_in[15];
    const float* b_aux1  = (const float*)d_in[16];
    const float* W_aux2  = (const float*)d_in[17];
    const float* b_aux2  = (const float*)d_in[18];

    float* out_mean  = (float*)d_out;
    float* out_lnvar = out_mean + NROWS;
    float* out_x     = out_lnvar + NROWS;

    unsigned short* wpack = (unsigned short*)d_ws;           // 384KB bf16
    float* biasH = (float*)((char*)d_ws + 3 * 32 * 256 * 8 * 2);

    prep_k<<<96, 256, 0, stream>>>(W_feat1, W_feat2, W_xim1, W_xil1,
                                   b_xim1, b_xil1, wpack, biasH);
    fused_k<<<512, 768, 0, stream>>>(data, omega, eps, wpack, biasH,
                                     b_feat1, b_feat2, W_feat1 + 256 * 256,
                                     W_xim2, b_xim2, W_xil2, b_xil2,
                                     W_aux1, b_aux1, W_aux2, b_aux2,
                                     out_mean, out_lnvar, out_x);
}

// Round 9
// 140.429 us; speedup vs baseline: 1.2027x; 1.2027x over previous
//
#include <hip/hip_runtime.h>
#include <math.h>

#define NROWS 16384
#define DT_C 0.01f

typedef short s16x8 __attribute__((ext_vector_type(8)));
typedef float f32x4 __attribute__((ext_vector_type(4)));
typedef float f32x2 __attribute__((ext_vector_type(2)));

__device__ __forceinline__ unsigned short f2bf(float f) {
    unsigned u = __float_as_uint(f);
    u += 0x7fffu + ((u >> 16) & 1u);
    return (unsigned short)(u >> 16);
}
__device__ __forceinline__ unsigned pack2bf(float a, float b) {
    return (unsigned)f2bf(a) | ((unsigned)f2bf(b) << 16);
}
// VALU-pipe cross-lane adds via DPP (no LDS pipe). 8-lane sum:
// xor1 (0xB1), xor2 (0x4E), row_half_mirror (0x141).
template <int CTRL>
__device__ __forceinline__ float dppadd(float v) {
    int x = __builtin_amdgcn_update_dpp(0, __float_as_int(v), CTRL, 0xF, 0xF, true);
    return v + __int_as_float(x);
}
__device__ __forceinline__ float sum8(float p) {
    p = dppadd<0xB1>(p);
    p = dppadd<0x4E>(p);
    p = dppadd<0x141>(p);
    return p;
}

// ---------------------------------------------------------------------------
// Prep: pack stage-B weights to bf16 flat [stage][k8][n][8] (k = k8*8+j).
// s=0: W_feat1[0:256], s=1: W_feat2, s=2: [W_xim1 | W_xil1].
// ---------------------------------------------------------------------------
__global__ __launch_bounds__(256) void prep_k(
    const float* __restrict__ Wf1, const float* __restrict__ Wf2,
    const float* __restrict__ Wm1, const float* __restrict__ Wl1,
    const float* __restrict__ bm1, const float* __restrict__ bl1,
    unsigned short* __restrict__ wpack, float* __restrict__ biasH)
{
    const int id = blockIdx.x * 256 + threadIdx.x;   // 0..24575
    const int n  = id & 255;
    const int k8 = (id >> 8) & 31;
    const int s  = id >> 13;

    unsigned short tmp[8];
    #pragma unroll
    for (int j = 0; j < 8; ++j) {
        const int k = k8 * 8 + j;
        float v;
        if (s == 0)      v = Wf1[k * 256 + n];
        else if (s == 1) v = Wf2[k * 256 + n];
        else             v = (n < 128) ? Wm1[k * 128 + n] : Wl1[k * 128 + n - 128];
        tmp[j] = f2bf(v);
    }
    *(uint4*)&wpack[((s * 32 + k8) * 256 + n) * 8] = *(const uint4*)tmp;

    if (id < 256) biasH[id] = (id < 128) ? bm1[id] : bl1[id - 128];
}

// ---------------------------------------------------------------------------
// Fused kernel, per 32-row block (R0's serial structure, reordered):
//   stage data->LDS frags; MFMA h1->feat->heads; 128-dots -> xi;
//   then PAIRED-STEP ODE scan (two independent acc-evals per pair -> 2x ILP,
//   issue-bound per wave) with decay fused into the single xout write.
// ---------------------------------------------------------------------------
__global__ __launch_bounds__(256, 2) void fused_k(
    const float* __restrict__ data, const float* __restrict__ omega,
    const float* __restrict__ eps_g,
    const unsigned short* __restrict__ wpack, const float* __restrict__ biasH,
    const float* __restrict__ bf1, const float* __restrict__ bf2,
    const float* __restrict__ w256g,
    const float* __restrict__ Wm2, const float* __restrict__ bm2,
    const float* __restrict__ Wl2, const float* __restrict__ bl2,
    const float* __restrict__ Wa1, const float* __restrict__ ba1,
    const float* __restrict__ Wa2, const float* __restrict__ ba2,
    float* __restrict__ out_mean, float* __restrict__ out_lnvar,
    float* __restrict__ xout)
{
    // 32.25KB LDS: headsF aliases As1+Hs (dead by heads phase)
    __shared__ __align__(16) unsigned char smem[33024];
    unsigned short* As1 = (unsigned short*)smem;            // 16KB frags: data, then feat
    unsigned short* Hs  = (unsigned short*)(smem + 16384);  // 16KB frags: h1
    float* headsF = (float*)smem;                           // 32KB alias: heads f32
    float* omg = (float*)(smem + 32768);
    float* xiS = omg + 32;

    const int tid  = threadIdx.x;
    const int wid  = tid >> 6;
    const int lane = tid & 63;
    const int ln   = lane & 15;
    const int quad = lane >> 4;
    const int r0   = blockIdx.x * 32;

    // ---- stage data -> As1 (coalesced, swizzled frag pack)
    {
        #pragma unroll
        for (int g2 = 0; g2 < 8; ++g2) {
            const int unit = g2 * 256 + tid;     // 16B unit over 32x256 f32
            const int m    = unit >> 6;
            const int c16  = unit & 63;
            const int kblk = c16 >> 1;
            const int h    = c16 & 1;
            const float4 v = *(const float4*)&data[(size_t)(r0 + m) * 256 + c16 * 4];
            unsigned* d = (unsigned*)&As1[((kblk * 32) + (m ^ (kblk & 7))) * 8 + h * 4];
            d[0] = pack2bf(v.x, v.y);
            d[1] = pack2bf(v.z, v.w);
        }
        if (tid < 32) omg[tid] = omega[r0 + tid];
    }
    __syncthreads();                               // B0: As1 + omg ready

    // ---- MFMA phases
    f32x4 acc[2][4];

    auto seed = [&](const float* bias) {
        #pragma unroll
        for (int nt = 0; nt < 4; ++nt) {
            const float b = bias[wid * 64 + nt * 16 + ln];
            acc[0][nt] = f32x4{b, b, b, b};
            acc[1][nt] = acc[0][nt];
        }
    };

    // A-frags from LDS, B-frags straight from global (L2-resident)
    auto run_stage = [&](const unsigned short* Ap, const unsigned short* wp) {
        #pragma unroll
        for (int c = 0; c < 4; ++c) {
            #pragma unroll
            for (int kk = 0; kk < 2; ++kk) {
                const int kb   = kk * 4 + quad;
                const int kblk = c * 8 + kb;
                const int f    = kblk & 7;
                s16x8 b0 = *(const s16x8*)&wp[((size_t)(kblk * 256) + wid * 64 + 0 * 16 + ln) * 8];
                s16x8 b1 = *(const s16x8*)&wp[((size_t)(kblk * 256) + wid * 64 + 1 * 16 + ln) * 8];
                s16x8 b2 = *(const s16x8*)&wp[((size_t)(kblk * 256) + wid * 64 + 2 * 16 + ln) * 8];
                s16x8 b3 = *(const s16x8*)&wp[((size_t)(kblk * 256) + wid * 64 + 3 * 16 + ln) * 8];
                s16x8 a0 = *(const s16x8*)&Ap[(kblk * 32 + (ln ^ f)) * 8];
                s16x8 a1 = *(const s16x8*)&Ap[(kblk * 32 + ((ln ^ f) + 16)) * 8];
                acc[0][0] = __builtin_amdgcn_mfma_f32_16x16x32_bf16(a0, b0, acc[0][0], 0, 0, 0);
                acc[1][0] = __builtin_amdgcn_mfma_f32_16x16x32_bf16(a1, b0, acc[1][0], 0, 0, 0);
                acc[0][1] = __builtin_amdgcn_mfma_f32_16x16x32_bf16(a0, b1, acc[0][1], 0, 0, 0);
                acc[1][1] = __builtin_amdgcn_mfma_f32_16x16x32_bf16(a1, b1, acc[1][1], 0, 0, 0);
                acc[0][2] = __builtin_amdgcn_mfma_f32_16x16x32_bf16(a0, b2, acc[0][2], 0, 0, 0);
                acc[1][2] = __builtin_amdgcn_mfma_f32_16x16x32_bf16(a1, b2, acc[1][2], 0, 0, 0);
                acc[0][3] = __builtin_amdgcn_mfma_f32_16x16x32_bf16(a0, b3, acc[0][3], 0, 0, 0);
                acc[1][3] = __builtin_amdgcn_mfma_f32_16x16x32_bf16(a1, b3, acc[1][3], 0, 0, 0);
            }
        }
    };

    auto write_packed = [&](unsigned short* dst, bool addOm) {
        #pragma unroll
        for (int nt = 0; nt < 4; ++nt) {
            const int col = wid * 64 + nt * 16 + ln;
            const int kg  = col >> 3, f = kg & 7, jj = col & 7;
            const float wo = addOm ? w256g[col] : 0.f;
            #pragma unroll
            for (int mt = 0; mt < 2; ++mt) {
                #pragma unroll
                for (int r = 0; r < 4; ++r) {
                    const int row = mt * 16 + quad * 4 + r;
                    float v = acc[mt][nt][r];
                    if (addOm) v = fmaf(omg[row], wo, v);
                    v = fmaxf(v, 0.f);
                    dst[(kg * 32 + (row ^ f)) * 8 + jj] = f2bf(v);
                }
            }
        }
    };

    seed(bf1);
    run_stage(As1, wpack);
    write_packed(Hs, true);
    __syncthreads();                               // B1: Hs ready
    seed(bf2);
    run_stage(Hs, wpack + 65536);
    write_packed(As1, false);
    __syncthreads();                               // B2: As1(feat) ready
    seed(biasH);
    run_stage(As1, wpack + 131072);
    __syncthreads();                               // B3a: all waves done with As1/Hs (alias!)
    #pragma unroll
    for (int nt = 0; nt < 4; ++nt) {
        const int col = wid * 64 + nt * 16 + ln;
        #pragma unroll
        for (int mt = 0; mt < 2; ++mt) {
            #pragma unroll
            for (int r = 0; r < 4; ++r) {
                const int row = mt * 16 + quad * 4 + r;
                headsF[row * 256 + ((col + row * 8) & 255)] = fmaxf(acc[mt][nt][r], 0.f);
            }
        }
    }
    __syncthreads();                               // B3: heads ready

    // ---- 128-dot heads: 8 lanes/row -> xi
    {
        const int m = tid >> 3, l = tid & 7;
        float pm = 0.f, pl = 0.f;
        #pragma unroll
        for (int q = 0; q < 4; ++q) {
            const int c0 = l * 16 + q * 4;
            const float4 hm = *(const float4*)&headsF[m * 256 + ((c0 + m * 8) & 255)];
            const float4 wm = *(const float4*)&Wm2[c0];
            const float4 hl = *(const float4*)&headsF[m * 256 + ((128 + c0 + m * 8) & 255)];
            const float4 wl = *(const float4*)&Wl2[c0];
            pm = fmaf(hm.w, wm.w, fmaf(hm.z, wm.z, fmaf(hm.y, wm.y, fmaf(hm.x, wm.x, pm))));
            pl = fmaf(hl.w, wl.w, fmaf(hl.z, wl.z, fmaf(hl.y, wl.y, fmaf(hl.x, wl.x, pl))));
        }
        pm = sum8(pm);
        pl = sum8(pl);
        if (l == 0) {
            const float xm  = pm + bm2[0];
            const float mean = fmaxf(xm, 0.f) + log1pf(expf(-fabsf(xm)));
            const float lnv  = pl + bl2[0];
            out_mean[r0 + m]  = mean;
            out_lnvar[r0 + m] = lnv;
            float xi = mean + expf(0.5f * lnv) * eps_g[r0 + m];
            xiS[m] = fminf(fmaxf(xi, 0.f), 1.f);
        }
    }
    __syncthreads();                               // B4: xiS ready (last barrier)

    // ---- PAIRED-STEP ODE scan (8 lanes/row), decay fused, single write.
    // Leapfrog y_{t+2} = 2y_{t+1} - y_t + DT2*acc(y_t). State per pair:
    // (u=y_{2k}, v=y_{2k+1}, au=acc(u)). w=y_{2k+2} is computable from au
    // immediately, so acc(v) and acc(w) are INDEPENDENT -> their partial
    // chains + sum8 DPP trees interleave -> issue-bound, not latency-bound.
    // Identical fp ops as the sequential version (same fma/sum8 exprs).
    {
        const int r   = tid >> 3;
        const int l   = tid & 7;
        const int row = r0 + r;
        const float om = omg[r];
        const float pseed = ba2[0] * 0.125f;

        f32x2 w1v[4], Av[4], w2v[4];
        #pragma unroll
        for (int i = 0; i < 4; ++i) {
            const f32x2 w0 = *(const f32x2*)&Wa1[l * 8 + i * 2];
            const f32x2 bb = *(const f32x2*)&ba1[l * 8 + i * 2];
            w1v[i] = *(const f32x2*)&Wa1[64 + l * 8 + i * 2];
            w2v[i] = *(const f32x2*)&Wa2[l * 8 + i * 2];
            Av[i]  = f32x2{fmaf(om, w0.x, bb.x), fmaf(om, w0.y, bb.y)};
        }

        auto partial = [&](float y) -> float {
            const f32x2 y2 = f32x2{y, y};
            f32x2 acc2 = f32x2{pseed, 0.f};
            #pragma unroll
            for (int i = 0; i < 4; ++i) {
                f32x2 h = __builtin_elementwise_fma(y2, w1v[i], Av[i]);
                h = __builtin_elementwise_max(h, f32x2{0.f, 0.f});
                acc2 = __builtin_elementwise_fma(h, w2v[i], acc2);
            }
            return acc2.x + acc2.y;
        };

        const float xi   = xiS[r];
        const float dfac = expf(-xi * DT_C);
        const float df2  = dfac * dfac;
        const float y0   = data[(size_t)row * 256];
        const float DT2  = DT_C * DT_C;

        float u  = y0;                   // y_{2k}
        float v  = y0;                   // y_{2k+1}  (v0 = 0)
        float au = sum8(partial(u));     // acc(y_{2k})
        float du = 1.f;                  // dfac^(2k)

        float* orow = xout + (size_t)row * 256 + l * 4;
        for (int tb = 0; tb < 8; ++tb) {
            float cur[4];
            #pragma unroll
            for (int p = 0; p < 16; ++p) {             // 16 pairs = 32 steps
                const int j0 = 2 * p;
                if ((j0 >> 2) == l) cur[j0 & 3] = u * du;                    // y_{2k} decayed
                const float w = fmaf(DT2, au, fmaf(2.f, v, -u));             // y_{2k+2}
                if (((j0 + 1) >> 2) == l) cur[(j0 + 1) & 3] = v * (du * dfac); // y_{2k+1}
                float av_ = partial(v);                 // independent pair of
                float aw_ = partial(w);                 // MLP evaluations
                av_ = sum8(av_);
                aw_ = sum8(aw_);
                const float x = fmaf(DT2, av_, fmaf(2.f, w, -v));            // y_{2k+3}
                u = w; v = x; au = aw_;
                du *= df2;
            }
            *(float4*)&orow[tb * 32] = *(const float4*)cur;
        }
    }
}

// ---------------------------------------------------------------------------
extern "C" void kernel_launch(void* const* d_in, const int* in_sizes, int n_in,
                              void* d_out, int out_size, void* d_ws, size_t ws_size,
                              hipStream_t stream)
{
    const float* data    = (const float*)d_in[0];
    const float* omega   = (const float*)d_in[1];
    const float* eps     = (const float*)d_in[2];
    const float* W_feat1 = (const float*)d_in[3];
    const float* b_feat1 = (const float*)d_in[4];
    const float* W_feat2 = (const float*)d_in[5];
    const float* b_feat2 = (const float*)d_in[6];
    const float* W_xim1  = (const float*)d_in[7];
    const float* b_xim1  = (const float*)d_in[8];
    const float* W_xim2  = (const float*)d_in[9];
    const float* b_xim2  = (const float*)d_in[10];
    const float* W_xil1  = (const float*)d_in[11];
    const float* b_xil1  = (const float*)d_in[12];
    const float* W_xil2  = (const float*)d_in[13];
    const float* b_xil2  = (const float*)d_in[14];
    const float* W_aux1  = (const float*)d_in[15];
    const float* b_aux1  = (const float*)d_in[16];
    const float* W_aux2  = (const float*)d_in[17];
    const float* b_aux2  = (const float*)d_in[18];

    float* out_mean  = (float*)d_out;
    float* out_lnvar = out_mean + NROWS;
    float* out_x     = out_lnvar + NROWS;

    unsigned short* wpack = (unsigned short*)d_ws;           // 384KB bf16
    float* biasH = (float*)((char*)d_ws + 3 * 32 * 256 * 8 * 2);

    prep_k<<<96, 256, 0, stream>>>(W_feat1, W_feat2, W_xim1, W_xil1,
                                   b_xim1, b_xil1, wpack, biasH);
    fused_k<<<512, 256, 0, stream>>>(data, omega, eps, wpack, biasH,
                                     b_feat1, b_feat2, W_feat1 + 256 * 256,
                                     W_xim2, b_xim2, W_xil2, b_xil2,
                                     W_aux1, b_aux1, W_aux2, b_aux2,
                                     out_mean, out_lnvar, out_x);
}

// Round 11
// 137.215 us; speedup vs baseline: 1.2309x; 1.0234x over previous
//
#include <hip/hip_runtime.h>
#include <math.h>

#define NROWS 16384
#define DT_C 0.01f

typedef short s16x8 __attribute__((ext_vector_type(8)));
typedef float f32x4 __attribute__((ext_vector_type(4)));
typedef float f32x2 __attribute__((ext_vector_type(2)));

__device__ __forceinline__ unsigned short f2bf(float f) {
    unsigned u = __float_as_uint(f);
    u += 0x7fffu + ((u >> 16) & 1u);
    return (unsigned short)(u >> 16);
}
__device__ __forceinline__ unsigned pack2bf(float a, float b) {
    return (unsigned)f2bf(a) | ((unsigned)f2bf(b) << 16);
}
// VALU-pipe cross-lane adds via DPP (no LDS pipe).
// sum4: xor1 (quad_perm 0xB1), xor2 (quad_perm 0x4E) — within each 4-lane group.
// sum8: + row_half_mirror (0x141).
template <int CTRL>
__device__ __forceinline__ float dppadd(float v) {
    int x = __builtin_amdgcn_update_dpp(0, __float_as_int(v), CTRL, 0xF, 0xF, true);
    return v + __int_as_float(x);
}
__device__ __forceinline__ float sum4(float p) {
    p = dppadd<0xB1>(p);
    p = dppadd<0x4E>(p);
    return p;
}
__device__ __forceinline__ float sum8(float p) {
    p = dppadd<0xB1>(p);
    p = dppadd<0x4E>(p);
    p = dppadd<0x141>(p);
    return p;
}

// ---------------------------------------------------------------------------
// Prep: pack stage-B weights to bf16 flat [stage][k8][n][8] (k = k8*8+j).
// s=0: W_feat1[0:256], s=1: W_feat2, s=2: [W_xim1 | W_xil1].
// ---------------------------------------------------------------------------
__global__ __launch_bounds__(256) void prep_k(
    const float* __restrict__ Wf1, const float* __restrict__ Wf2,
    const float* __restrict__ Wm1, const float* __restrict__ Wl1,
    const float* __restrict__ bm1, const float* __restrict__ bl1,
    unsigned short* __restrict__ wpack, float* __restrict__ biasH)
{
    const int id = blockIdx.x * 256 + threadIdx.x;   // 0..24575
    const int n  = id & 255;
    const int k8 = (id >> 8) & 31;
    const int s  = id >> 13;

    unsigned short tmp[8];
    #pragma unroll
    for (int j = 0; j < 8; ++j) {
        const int k = k8 * 8 + j;
        float v;
        if (s == 0)      v = Wf1[k * 256 + n];
        else if (s == 1) v = Wf2[k * 256 + n];
        else             v = (n < 128) ? Wm1[k * 128 + n] : Wl1[k * 128 + n - 128];
        tmp[j] = f2bf(v);
    }
    *(uint4*)&wpack[((s * 32 + k8) * 256 + n) * 8] = *(const uint4*)tmp;

    if (id < 256) biasH[id] = (id < 128) ? bm1[id] : bl1[id - 128];
}

// ---------------------------------------------------------------------------
// Fused kernel, 512 threads (8 waves) per 64-row block, grid 256 (1 block/CU):
//   stage data->LDS frags (M=64); MFMA h1->feat->heads — 8 waves x 32 cols
//   (acc[4][2]; B-panels read once per block, half the L2 traffic of 32-row
//   tiles); 128-dots -> xi; then waves 4-7 RETURN and waves 0-3 (one per
//   SIMD) run the ODE scan at 4 lanes/row (16 MLP units/lane, sum4 = 2
//   DPP-adds, split accumulators -> issue-bound at 1 wave/SIMD), decay fused
//   into the single xout write.
// ---------------------------------------------------------------------------
__global__ __launch_bounds__(512, 2) void fused_k(
    const float* __restrict__ data, const float* __restrict__ omega,
    const float* __restrict__ eps_g,
    const unsigned short* __restrict__ wpack, const float* __restrict__ biasH,
    const float* __restrict__ bf1, const float* __restrict__ bf2,
    const float* __restrict__ w256g,
    const float* __restrict__ Wm2, const float* __restrict__ bm2,
    const float* __restrict__ Wl2, const float* __restrict__ bl2,
    const float* __restrict__ Wa1, const float* __restrict__ ba1,
    const float* __restrict__ Wa2, const float* __restrict__ ba2,
    float* __restrict__ out_mean, float* __restrict__ out_lnvar,
    float* __restrict__ xout)
{
    // 64.5KB LDS: headsF (64KB) aliases As1+Hs (dead by heads phase)
    __shared__ __align__(16) unsigned char smem[66048];
    unsigned short* As1 = (unsigned short*)smem;            // 32KB frags: data, then feat
    unsigned short* Hs  = (unsigned short*)(smem + 32768);  // 32KB frags: h1
    float* headsF = (float*)smem;                           // 64KB alias: heads f32
    float* omg = (float*)(smem + 65536);                    // [64]
    float* xiS = (float*)(smem + 65792);                    // [64]

    const int tid  = threadIdx.x;
    const int wid  = tid >> 6;          // 0..7
    const int lane = tid & 63;
    const int ln   = lane & 15;
    const int quad = lane >> 4;
    const int r0   = blockIdx.x * 64;

    // ---- stage data -> As1 (coalesced, swizzled frag pack), 64 rows
    {
        #pragma unroll
        for (int g2 = 0; g2 < 8; ++g2) {
            const int unit = g2 * 512 + tid;     // 16B unit over 64x256 f32
            const int m    = unit >> 6;          // row 0..63
            const int c16  = unit & 63;
            const int kblk = c16 >> 1;
            const int h    = c16 & 1;
            const float4 v = *(const float4*)&data[(size_t)(r0 + m) * 256 + c16 * 4];
            unsigned* d = (unsigned*)&As1[((kblk * 64) + (m ^ (kblk & 7))) * 8 + h * 4];
            d[0] = pack2bf(v.x, v.y);
            d[1] = pack2bf(v.z, v.w);
        }
        if (tid < 64) omg[tid] = omega[r0 + tid];
    }
    __syncthreads();                               // B0: As1 + omg ready

    // ---- MFMA phases: 8 waves x 32 cols (2 n-tiles), M=64 (4 m-tiles)
    f32x4 acc[4][2];

    auto seed = [&](const float* bias) {
        #pragma unroll
        for (int nt = 0; nt < 2; ++nt) {
            const float b = bias[wid * 32 + nt * 16 + ln];
            #pragma unroll
            for (int mt = 0; mt < 4; ++mt) acc[mt][nt] = f32x4{b, b, b, b};
        }
    };

    // A-frags from LDS, B-frags straight from global (L2-resident; each
    // column panel read once per block -> half the L2 traffic of 32-row tiles)
    auto run_stage = [&](const unsigned short* Ap, const unsigned short* wp) {
        #pragma unroll
        for (int c = 0; c < 4; ++c) {
            #pragma unroll
            for (int kk = 0; kk < 2; ++kk) {
                const int kb   = kk * 4 + quad;
                const int kblk = c * 8 + kb;
                const int f    = kblk & 7;
                s16x8 b0 = *(const s16x8*)&wp[((size_t)(kblk * 256) + wid * 32 + 0 * 16 + ln) * 8];
                s16x8 b1 = *(const s16x8*)&wp[((size_t)(kblk * 256) + wid * 32 + 1 * 16 + ln) * 8];
                #pragma unroll
                for (int mt = 0; mt < 4; ++mt) {
                    s16x8 a = *(const s16x8*)&Ap[((size_t)kblk * 64 + ((ln ^ f) + 16 * mt)) * 8];
                    acc[mt][0] = __builtin_amdgcn_mfma_f32_16x16x32_bf16(a, b0, acc[mt][0], 0, 0, 0);
                    acc[mt][1] = __builtin_amdgcn_mfma_f32_16x16x32_bf16(a, b1, acc[mt][1], 0, 0, 0);
                }
            }
        }
    };

    auto write_packed = [&](unsigned short* dst, bool addOm) {
        #pragma unroll
        for (int nt = 0; nt < 2; ++nt) {
            const int col = wid * 32 + nt * 16 + ln;
            const int kg  = col >> 3, f = kg & 7, jj = col & 7;
            const float wo = addOm ? w256g[col] : 0.f;
            #pragma unroll
            for (int mt = 0; mt < 4; ++mt) {
                #pragma unroll
                for (int r = 0; r < 4; ++r) {
                    const int row = mt * 16 + quad * 4 + r;
                    float v = acc[mt][nt][r];
                    if (addOm) v = fmaf(omg[row], wo, v);
                    v = fmaxf(v, 0.f);
                    dst[(kg * 64 + (row ^ f)) * 8 + jj] = f2bf(v);
                }
            }
        }
    };

    seed(bf1);
    run_stage(As1, wpack);
    write_packed(Hs, true);
    __syncthreads();                               // B1: Hs ready
    seed(bf2);
    run_stage(Hs, wpack + 65536);
    write_packed(As1, false);
    __syncthreads();                               // B2: As1(feat) ready
    seed(biasH);
    run_stage(As1, wpack + 131072);
    __syncthreads();                               // B3a: all waves done with As1/Hs (alias!)
    #pragma unroll
    for (int nt = 0; nt < 2; ++nt) {
        const int col = wid * 32 + nt * 16 + ln;
        #pragma unroll
        for (int mt = 0; mt < 4; ++mt) {
            #pragma unroll
            for (int r = 0; r < 4; ++r) {
                const int row = mt * 16 + quad * 4 + r;
                headsF[row * 256 + ((col + row * 8) & 255)] = fmaxf(acc[mt][nt][r], 0.f);
            }
        }
    }
    __syncthreads();                               // B3: heads ready

    // ---- 128-dot heads: 8 lanes/row, 64 rows -> xi
    {
        const int m = tid >> 3, l = tid & 7;
        float pm = 0.f, pl = 0.f;
        #pragma unroll
        for (int q = 0; q < 4; ++q) {
            const int c0 = l * 16 + q * 4;
            const float4 hm = *(const float4*)&headsF[m * 256 + ((c0 + m * 8) & 255)];
            const float4 wm = *(const float4*)&Wm2[c0];
            const float4 hl = *(const float4*)&headsF[m * 256 + ((128 + c0 + m * 8) & 255)];
            const float4 wl = *(const float4*)&Wl2[c0];
            pm = fmaf(hm.w, wm.w, fmaf(hm.z, wm.z, fmaf(hm.y, wm.y, fmaf(hm.x, wm.x, pm))));
            pl = fmaf(hl.w, wl.w, fmaf(hl.z, wl.z, fmaf(hl.y, wl.y, fmaf(hl.x, wl.x, pl))));
        }
        pm = sum8(pm);
        pl = sum8(pl);
        if (l == 0) {
            const float xm  = pm + bm2[0];
            const float mean = fmaxf(xm, 0.f) + log1pf(expf(-fabsf(xm)));
            const float lnv  = pl + bl2[0];
            out_mean[r0 + m]  = mean;
            out_lnvar[r0 + m] = lnv;
            float xi = mean + expf(0.5f * lnv) * eps_g[r0 + m];
            xiS[m] = fminf(fmaxf(xi, 0.f), 1.f);
        }
    }
    __syncthreads();                               // B4: xiS ready (LAST barrier)

    // ---- waves 4-7 done; waves 0-3 (one per SIMD) scan at 4 lanes/row.
    if (tid >= 256) return;

    // ODE scan, R0's proven pipelined recurrence (pn computed one step ahead),
    // 16 MLP units/lane in f32x2 pairs, SPLIT accumulators (shorter dep chain),
    // sum4 = 2 DPP-adds. Decay fused into the single xout write.
    {
        const int r   = tid >> 2;        // row 0..63
        const int l   = tid & 3;         // 4 lanes/row, units i = l*16..l*16+15
        const int row = r0 + r;
        const float om = omg[r];
        const float pseed = ba2[0] * 0.25f;

        f32x2 w1v[8], Av[8], w2v[8];
        #pragma unroll
        for (int i = 0; i < 8; ++i) {
            const f32x2 w0 = *(const f32x2*)&Wa1[l * 16 + i * 2];
            const f32x2 bb = *(const f32x2*)&ba1[l * 16 + i * 2];
            w1v[i] = *(const f32x2*)&Wa1[64 + l * 16 + i * 2];
            w2v[i] = *(const f32x2*)&Wa2[l * 16 + i * 2];
            Av[i]  = f32x2{fmaf(om, w0.x, bb.x), fmaf(om, w0.y, bb.y)};
        }

        auto partial = [&](float y) -> float {
            const f32x2 y2 = f32x2{y, y};
            f32x2 aA = f32x2{pseed, 0.f};
            f32x2 aB = f32x2{0.f, 0.f};
            #pragma unroll
            for (int i = 0; i < 4; ++i) {
                f32x2 h = __builtin_elementwise_fma(y2, w1v[i], Av[i]);
                h = __builtin_elementwise_max(h, f32x2{0.f, 0.f});
                aA = __builtin_elementwise_fma(h, w2v[i], aA);
            }
            #pragma unroll
            for (int i = 4; i < 8; ++i) {
                f32x2 g = __builtin_elementwise_fma(y2, w1v[i], Av[i]);
                g = __builtin_elementwise_max(g, f32x2{0.f, 0.f});
                aB = __builtin_elementwise_fma(g, w2v[i], aB);
            }
            return (aA.x + aA.y) + (aB.x + aB.y);
        };

        const float xi   = xiS[r];
        const float dfac = expf(-xi * DT_C);
        const float y0   = data[(size_t)row * 256];
        float ym = y0;          // y_t
        float yc = y0;          // y_{t+1}  (v0 = 0)
        float d  = 1.f;         // dfac^t
        const float DT2 = DT_C * DT_C;
        float pr = sum4(partial(ym));

        float* orow = xout + (size_t)row * 256 + l * 4;
        for (int tb = 0; tb < 16; ++tb) {
            float cur[4];
            #pragma unroll
            for (int j = 0; j < 16; ++j) {
                if ((j >> 2) == l) cur[j & 3] = ym * d;    // y_t * dfac^t
                float pn = sum4(partial(yc));
                const float ynext = fmaf(DT2, pr, fmaf(2.f, yc, -ym));
                ym = yc; yc = ynext; pr = pn;              // pr consumed next step
                d *= dfac;
            }
            *(float4*)&orow[tb * 16] = *(const float4*)cur;
        }
    }
}

// ---------------------------------------------------------------------------
extern "C" void kernel_launch(void* const* d_in, const int* in_sizes, int n_in,
                              void* d_out, int out_size, void* d_ws, size_t ws_size,
                              hipStream_t stream)
{
    const float* data    = (const float*)d_in[0];
    const float* omega   = (const float*)d_in[1];
    const float* eps     = (const float*)d_in[2];
    const float* W_feat1 = (const float*)d_in[3];
    const float* b_feat1 = (const float*)d_in[4];
    const float* W_feat2 = (const float*)d_in[5];
    const float* b_feat2 = (const float*)d_in[6];
    const float* W_xim1  = (const float*)d_in[7];
    const float* b_xim1  = (const float*)d_in[8];
    const float* W_xim2  = (const float*)d_in[9];
    const float* b_xim2  = (const float*)d_in[10];
    const float* W_xil1  = (const float*)d_in[11];
    const float* b_xil1  = (const float*)d_in[12];
    const float* W_xil2  = (const float*)d_in[13];
    const float* b_xil2  = (const float*)d_in[14];
    const float* W_aux1  = (const float*)d_in[15];
    const float* b_aux1  = (const float*)d_in[16];
    const float* W_aux2  = (const float*)d_in[17];
    const float* b_aux2  = (const float*)d_in[18];

    float* out_mean  = (float*)d_out;
    float* out_lnvar = out_mean + NROWS;
    float* out_x     = out_lnvar + NROWS;

    unsigned short* wpack = (unsigned short*)d_ws;           // 384KB bf16
    float* biasH = (float*)((char*)d_ws + 3 * 32 * 256 * 8 * 2);

    prep_k<<<96, 256, 0, stream>>>(W_feat1, W_feat2, W_xim1, W_xil1,
                                   b_xim1, b_xil1, wpack, biasH);
    fused_k<<<256, 512, 0, stream>>>(data, omega, eps, wpack, biasH,
                                     b_feat1, b_feat2, W_feat1 + 256 * 256,
                                     W_xim2, b_xim2, W_xil2, b_xil2,
                                     W_aux1, b_aux1, W_aux2, b_aux2,
                                     out_mean, out_lnvar, out_x);
}